// Round 1
// baseline (1063.189 us; speedup 1.0000x reference)
//
#include <hip/hip_runtime.h>
#include <hip/hip_bf16.h>

typedef unsigned short u16;
typedef unsigned int   u32;

// Problem dims (fixed by setup_inputs): B=128, T=512, V=50000, NT=24, E=128, H=256, Hd=128
#define NB   128
#define NT_  24
#define TT   512

__device__ __forceinline__ float sigf(float x)  { return 1.0f / (1.0f + __expf(-x)); }
__device__ __forceinline__ float tanhf_(float x){ return 1.0f - 2.0f / (__expf(2.0f * x) + 1.0f); }

__device__ __forceinline__ u16 f2bf(float x) {
  __hip_bfloat16 h = __float2bfloat16(x);
  return *reinterpret_cast<u16*>(&h);
}
__device__ __forceinline__ float bf2f(u16 u) { return __uint_as_float(((u32)u) << 16); }
__device__ __forceinline__ u32 pk2(float a, float b) {
  return (u32)f2bf(a) | ((u32)f2bf(b) << 16);
}

// ---------------------------------------------------------------------------
// K2: fused embedding-gather + input gate GEMM.
//   G[m][j] = sum_k emb[x[m]][k] * Wih_dir[j'][k] + (bih+bhh)[j'],  m = b*T+t
//   j in [0,1024): j<512 -> forward dir, else backward. Stored bf16.
// 128x128 tile, K staged in 2 chunks of 64, 8x8 outputs per thread.
// ---------------------------------------------------------------------------
__global__ __launch_bounds__(256, 2) void gates_gemm_k(
    const int* __restrict__ x, const float* __restrict__ emb,
    const float* __restrict__ Wih_f, const float* __restrict__ Wih_b,
    const float* __restrict__ bih_f, const float* __restrict__ bhh_f,
    const float* __restrict__ bih_b, const float* __restrict__ bhh_b,
    u16* __restrict__ Gout)
{
  __shared__ float As[128][69];                 // [row][k], stride 69 -> conflict-free a reads
  __shared__ __align__(16) float Bs[64][132];   // [k][col], stride 132 -> aligned float4 b reads
  const int tid = threadIdx.x;
  const int tx = tid & 15;   // col group / k-pos in staging
  const int ty = tid >> 4;   // row group / row in staging
  const int m0 = blockIdx.y * 128;
  const int n0 = blockIdx.x * 128;

  float acc[8][8];
#pragma unroll
  for (int i = 0; i < 8; ++i)
#pragma unroll
    for (int j = 0; j < 8; ++j) acc[i][j] = 0.0f;

  for (int kc = 0; kc < 128; kc += 64) {
    __syncthreads();
    // stage A: 128 rows x 64 k (embedding gather)
#pragma unroll
    for (int it = 0; it < 8; ++it) {
      int row = ty + 16 * it;
      int token = x[m0 + row];
      float4 v = *(const float4*)&emb[(size_t)token * 128 + kc + tx * 4];
      As[row][tx*4+0] = v.x; As[row][tx*4+1] = v.y;
      As[row][tx*4+2] = v.z; As[row][tx*4+3] = v.w;
    }
    // stage B: 128 cols x 64 k (Wih rows, transposed into [k][col])
#pragma unroll
    for (int it = 0; it < 8; ++it) {
      int jl = ty + 16 * it;
      int j = n0 + jl;
      const float* Wsrc = (j < 512) ? (Wih_f + (size_t)j * 128)
                                    : (Wih_b + (size_t)(j - 512) * 128);
      float4 v = *(const float4*)&Wsrc[kc + tx * 4];
      Bs[tx*4+0][jl] = v.x; Bs[tx*4+1][jl] = v.y;
      Bs[tx*4+2][jl] = v.z; Bs[tx*4+3][jl] = v.w;
    }
    __syncthreads();
#pragma unroll 4
    for (int k = 0; k < 64; ++k) {
      float a_[8];
#pragma unroll
      for (int i = 0; i < 8; ++i) a_[i] = As[8 * ty + i][k];
      float4 b0 = *(const float4*)&Bs[k][8 * tx];
      float4 b1 = *(const float4*)&Bs[k][8 * tx + 4];
#pragma unroll
      for (int i = 0; i < 8; ++i) {
        acc[i][0] += a_[i] * b0.x; acc[i][1] += a_[i] * b0.y;
        acc[i][2] += a_[i] * b0.z; acc[i][3] += a_[i] * b0.w;
        acc[i][4] += a_[i] * b1.x; acc[i][5] += a_[i] * b1.y;
        acc[i][6] += a_[i] * b1.z; acc[i][7] += a_[i] * b1.w;
      }
    }
  }

  float bias_[8];
#pragma unroll
  for (int jj = 0; jj < 8; ++jj) {
    int j = n0 + 8 * tx + jj;
    bias_[jj] = (j < 512) ? (bih_f[j] + bhh_f[j]) : (bih_b[j - 512] + bhh_b[j - 512]);
  }
#pragma unroll
  for (int i = 0; i < 8; ++i) {
    int m = m0 + 8 * ty + i;
    uint4 p;
    p.x = pk2(acc[i][0] + bias_[0], acc[i][1] + bias_[1]);
    p.y = pk2(acc[i][2] + bias_[2], acc[i][3] + bias_[3]);
    p.z = pk2(acc[i][4] + bias_[4], acc[i][5] + bias_[5]);
    p.w = pk2(acc[i][6] + bias_[6], acc[i][7] + bias_[7]);
    *(uint4*)&Gout[(size_t)m * 1024 + n0 + 8 * tx] = p;
  }
}

// ---------------------------------------------------------------------------
// K3: the sequential LSTM recurrence. One block per (direction, sample):
// 256 blocks ~ 256 CUs. 512 threads; thread j owns gate j and keeps its
// Whh row (128 f32) in registers. h broadcast via LDS; c in regs of j<128.
// ---------------------------------------------------------------------------
__global__ __launch_bounds__(512, 2) void lstm_k(
    const u16* __restrict__ G, const float* __restrict__ Whh_f,
    const float* __restrict__ Whh_b, u16* __restrict__ Hout)
{
  const int bid = blockIdx.x;
  const int dir = bid >> 7;     // 0 = forward, 1 = backward
  const int b   = bid & 127;
  const int j   = threadIdx.x;  // 0..511 (gate index)
  const float* Whh = dir ? Whh_b : Whh_f;

  float w[128];
#pragma unroll
  for (int i4 = 0; i4 < 32; ++i4) {
    float4 v = *(const float4*)&Whh[(size_t)j * 128 + i4 * 4];
    w[4*i4+0] = v.x; w[4*i4+1] = v.y; w[4*i4+2] = v.z; w[4*i4+3] = v.w;
  }

  __shared__ __align__(16) float hs[128];
  __shared__ float gact[512];
  if (j < 128) hs[j] = 0.0f;
  float c = 0.0f;
  __syncthreads();

  const size_t gbase = (size_t)b * TT * 1024 + (size_t)dir * 512 + j;
  int t = dir ? (TT - 1) : 0;
  const int tstep = dir ? -1 : 1;
  u16 gb = G[gbase + (size_t)t * 1024];

  for (int step = 0; step < TT; ++step) {
    float gpre = bf2f(gb);
    if (step < TT - 1) gb = G[gbase + (size_t)(t + tstep) * 1024];  // prefetch next step

    float acc0 = 0.f, acc1 = 0.f, acc2 = 0.f, acc3 = 0.f;
    const float4* h4 = (const float4*)hs;
#pragma unroll
    for (int i4 = 0; i4 < 32; i4 += 4) {
      float4 h0 = h4[i4+0], h1 = h4[i4+1], h2 = h4[i4+2], h3 = h4[i4+3];
      acc0 += w[4*i4+ 0]*h0.x + w[4*i4+ 1]*h0.y + w[4*i4+ 2]*h0.z + w[4*i4+ 3]*h0.w;
      acc1 += w[4*i4+ 4]*h1.x + w[4*i4+ 5]*h1.y + w[4*i4+ 6]*h1.z + w[4*i4+ 7]*h1.w;
      acc2 += w[4*i4+ 8]*h2.x + w[4*i4+ 9]*h2.y + w[4*i4+10]*h2.z + w[4*i4+11]*h2.w;
      acc3 += w[4*i4+12]*h3.x + w[4*i4+13]*h3.y + w[4*i4+14]*h3.z + w[4*i4+15]*h3.w;
    }
    float g = gpre + ((acc0 + acc1) + (acc2 + acc3));
    int gate = j >> 7;                       // 0=i 1=f 2=g 3=o (uniform per wave)
    float a = (gate == 2) ? tanhf_(g) : sigf(g);
    gact[j] = a;
    __syncthreads();
    if (j < 128) {
      float iv = gact[j], fv = gact[128 + j], gv = gact[256 + j], ov = gact[384 + j];
      c = fv * c + iv * gv;
      float hv = ov * tanhf_(c);
      hs[j] = hv;
      Hout[((size_t)(b * TT + t)) * 256 + dir * 128 + j] = f2bf(hv);
    }
    __syncthreads();
    t += tstep;
  }
}

// ---------------------------------------------------------------------------
// K4: emissions = h @ W_out^T + b_out.  One thread per (b,t) row; W_out in LDS.
// ---------------------------------------------------------------------------
__global__ __launch_bounds__(256) void emis_k(
    const u16* __restrict__ Hb, const float* __restrict__ W_out,
    const float* __restrict__ b_out, float* __restrict__ em)
{
  __shared__ __align__(16) float wl[24 * 256];
  __shared__ float bo[24];
  const int tid = threadIdx.x;
#pragma unroll
  for (int i = 0; i < 6; ++i) {
    int f4 = tid + i * 256;
    *(float4*)&wl[f4 * 4] = *(const float4*)&W_out[f4 * 4];
  }
  if (tid < 24) bo[tid] = b_out[tid];
  __syncthreads();

  const int m = blockIdx.x * 256 + tid;
  float acc[24];
#pragma unroll
  for (int tg = 0; tg < 24; ++tg) acc[tg] = bo[tg];

  const u16* hrow = Hb + (size_t)m * 256;
  for (int k8 = 0; k8 < 32; ++k8) {
    uint4 hv = *(const uint4*)(hrow + k8 * 8);
    float h0 = bf2f((u16)(hv.x & 0xffff)), h1 = bf2f((u16)(hv.x >> 16));
    float h2 = bf2f((u16)(hv.y & 0xffff)), h3 = bf2f((u16)(hv.y >> 16));
    float h4 = bf2f((u16)(hv.z & 0xffff)), h5 = bf2f((u16)(hv.z >> 16));
    float h6 = bf2f((u16)(hv.w & 0xffff)), h7 = bf2f((u16)(hv.w >> 16));
#pragma unroll
    for (int tg = 0; tg < 24; ++tg) {
      const float* wr = &wl[tg * 256 + k8 * 8];
      float4 w0 = *(const float4*)wr;
      float4 w1 = *(const float4*)(wr + 4);
      acc[tg] += h0*w0.x + h1*w0.y + h2*w0.z + h3*w0.w
               + h4*w1.x + h5*w1.y + h6*w1.z + h7*w1.w;
    }
  }
#pragma unroll
  for (int t6 = 0; t6 < 6; ++t6) {
    float4 o;
    o.x = acc[t6*4+0]; o.y = acc[t6*4+1]; o.z = acc[t6*4+2]; o.w = acc[t6*4+3];
    *(float4*)&em[(size_t)m * 24 + t6 * 4] = o;
  }
}

// ---------------------------------------------------------------------------
// K5: CRF forward scan + gold score + mean reduction. One block per sample.
// mask dtype auto-detected: word0 == 1 -> int32 mask, else packed bytes
// (mask[0][0] is always true since lengths >= T/2).
// ---------------------------------------------------------------------------
__device__ __forceinline__ int get_mask(const void* mp, int idx, bool byte_mode) {
  return byte_mode ? (int)((const unsigned char*)mp)[idx] : ((const int*)mp)[idx];
}

__global__ __launch_bounds__(64) void crf_k(
    const float* __restrict__ em, const int* __restrict__ tags,
    const void* __restrict__ maskp, const float* __restrict__ trans,
    const float* __restrict__ start_tr, const float* __restrict__ end_tr,
    float* __restrict__ out)
{
  const int b = blockIdx.x;
  const int tid = threadIdx.x;
  __shared__ float tr[24 * 24];
  __shared__ float sc[24];
  __shared__ float lz;
  for (int i = tid; i < 24 * 24; i += 64) tr[i] = trans[i];
  const bool byte_mode = (*(const u32*)maskp != 1u);

  if (tid < 24) sc[tid] = start_tr[tid] + em[(size_t)(b * TT) * 24 + tid];
  __syncthreads();

  for (int t = 1; t < TT; ++t) {
    if (!get_mask(maskp, b * TT + t, byte_mode)) break;   // mask is a monotone prefix
    float ns = 0.f;
    if (tid < 24) {
      float v[24];
      float mx = -1e30f;
#pragma unroll
      for (int i = 0; i < 24; ++i) { v[i] = sc[i] + tr[i * 24 + tid]; mx = fmaxf(mx, v[i]); }
      float s = 0.f;
#pragma unroll
      for (int i = 0; i < 24; ++i) s += __expf(v[i] - mx);
      ns = em[((size_t)(b * TT + t)) * 24 + tid] + mx + __logf(s);
    }
    __syncthreads();
    if (tid < 24) sc[tid] = ns;
    __syncthreads();
  }

  if (tid == 0) {
    float mx = -1e30f;
    for (int i = 0; i < 24; ++i) mx = fmaxf(mx, sc[i] + end_tr[i]);
    float s = 0.f;
    for (int i = 0; i < 24; ++i) s += __expf(sc[i] + end_tr[i] - mx);
    lz = mx + __logf(s);
  }

  // gold score, parallel over the single 64-lane wave
  float part = 0.f;
  int cnt = 0;
  for (int t = tid; t < TT; t += 64) {
    int mt = get_mask(maskp, b * TT + t, byte_mode);
    cnt += mt;
    if (t >= 1 && mt) {
      int tp = tags[b * TT + t - 1], tc = tags[b * TT + t];
      part += tr[tp * 24 + tc] + em[((size_t)(b * TT + t)) * 24 + tc];
    }
  }
#pragma unroll
  for (int off = 32; off > 0; off >>= 1) {
    part += __shfl_down(part, off);
    cnt  += __shfl_down(cnt, off);
  }
  __syncthreads();
  if (tid == 0) {
    int t0g = tags[b * TT];
    float gold = start_tr[t0g] + em[(size_t)(b * TT) * 24 + t0g] + part;
    gold += end_tr[tags[b * TT + cnt - 1]];
    atomicAdd(out, (lz - gold) * (1.0f / 128.0f));
  }
}

// ---------------------------------------------------------------------------
extern "C" void kernel_launch(void* const* d_in, const int* in_sizes, int n_in,
                              void* d_out, int out_size, void* d_ws, size_t ws_size,
                              hipStream_t stream) {
  const int*   x     = (const int*)d_in[0];
  const int*   tags  = (const int*)d_in[1];
  const void*  mask  = d_in[2];
  const float* emb   = (const float*)d_in[3];
  const float* Wih_f = (const float*)d_in[4];
  const float* Whh_f = (const float*)d_in[5];
  const float* bih_f = (const float*)d_in[6];
  const float* bhh_f = (const float*)d_in[7];
  const float* Wih_b = (const float*)d_in[8];
  const float* Whh_b = (const float*)d_in[9];
  const float* bih_b = (const float*)d_in[10];
  const float* bhh_b = (const float*)d_in[11];
  const float* W_out = (const float*)d_in[12];
  const float* b_out = (const float*)d_in[13];
  const float* trans = (const float*)d_in[14];
  const float* st_tr = (const float*)d_in[15];
  const float* en_tr = (const float*)d_in[16];

  // Workspace layout (bytes): G bf16 134217728 | H bf16 33554432 | em f32 6291456
  u16*   Gb = (u16*)d_ws;                                 // [65536][1024] bf16
  u16*   Hb = Gb + (size_t)65536 * 1024;                  // [65536][256]  bf16
  float* em = (float*)(Hb + (size_t)65536 * 256);         // [65536][24]   f32

  dim3 gGemm(8, 512);   // N/128 x M/128
  gates_gemm_k<<<gGemm, 256, 0, stream>>>(x, emb, Wih_f, Wih_b, bih_f, bhh_f,
                                          bih_b, bhh_b, Gb);
  lstm_k<<<256, 512, 0, stream>>>(Gb, Whh_f, Whh_b, Hb);
  emis_k<<<256, 256, 0, stream>>>(Hb, W_out, b_out, em);
  hipMemsetAsync(d_out, 0, sizeof(float), stream);
  crf_k<<<128, 64, 0, stream>>>(em, tags, mask, trans, st_tr, en_tr, (float*)d_out);
}

// Round 2
// 828.346 us; speedup vs baseline: 1.2835x; 1.2835x over previous
//
#include <hip/hip_runtime.h>
#include <hip/hip_bf16.h>

typedef unsigned short u16;
typedef unsigned int   u32;
typedef _Float16 half2_t __attribute__((ext_vector_type(2)));
typedef short    bf16x8 __attribute__((ext_vector_type(8)));
typedef float    f32x4  __attribute__((ext_vector_type(4)));

// Problem dims: B=128, T=512, V=50000, NT=24, E=128, H=256, Hd=128
#define TT   512

__device__ __forceinline__ float sigf(float x)  { return 1.0f / (1.0f + __expf(-x)); }
__device__ __forceinline__ float tanhf_(float x){ return 1.0f - 2.0f / (__expf(2.0f * x) + 1.0f); }

__device__ __forceinline__ u16 f2bf(float x) {
  __hip_bfloat16 h = __float2bfloat16(x);
  return *reinterpret_cast<u16*>(&h);
}
__device__ __forceinline__ float bf2f(u16 u) { return __uint_as_float(((u32)u) << 16); }
__device__ __forceinline__ u32 pk2(float a, float b) {
  return (u32)f2bf(a) | ((u32)f2bf(b) << 16);
}
__device__ __forceinline__ u16 f2h(float x) {
  _Float16 h = (_Float16)x;
  union { _Float16 f; u16 u; } c; c.f = h; return c.u;
}
__device__ __forceinline__ half2_t u2h2(u32 v) {
  union { u32 u; half2_t h; } c; c.u = v; return c.h;
}

// ---------------------------------------------------------------------------
// K0: weight prep. Wb bf16 [1024][128] (Wih_f||Wih_b), Whh16 f16x2 [2][512][64],
// bias f32 [1024] = bih+bhh per dir.
// ---------------------------------------------------------------------------
__global__ __launch_bounds__(256) void prep_k(
    const float* __restrict__ Wih_f, const float* __restrict__ Wih_b,
    const float* __restrict__ Whh_f, const float* __restrict__ Whh_b,
    const float* __restrict__ bih_f, const float* __restrict__ bhh_f,
    const float* __restrict__ bih_b, const float* __restrict__ bhh_b,
    u16* __restrict__ Wb, u32* __restrict__ Whh16, float* __restrict__ bias)
{
  int i = blockIdx.x * 256 + threadIdx.x;   // 131072 threads
  {
    int n = i >> 7, k = i & 127;
    float v = (n < 512) ? Wih_f[n * 128 + k] : Wih_b[(n - 512) * 128 + k];
    Wb[i] = f2bf(v);
  }
  if (i < 65536) {
    int d = i >> 15, rem = i & 32767, r = rem >> 6, kp = rem & 63;
    const float* W = d ? Whh_b : Whh_f;
    float f0 = W[r * 128 + 2 * kp], f1 = W[r * 128 + 2 * kp + 1];
    Whh16[i] = (u32)f2h(f0) | ((u32)f2h(f1) << 16);
  }
  if (i < 1024) {
    int d = i >> 9, jj = i & 511;
    bias[i] = d ? (bih_b[jj] + bhh_b[jj]) : (bih_f[jj] + bhh_f[jj]);
  }
}

// ---------------------------------------------------------------------------
// K1: embedding gather -> bf16 xe [65536][128]
// ---------------------------------------------------------------------------
__global__ __launch_bounds__(256) void embed_k(
    const int* __restrict__ x, const float* __restrict__ emb, u16* __restrict__ xe)
{
  const int tid = threadIdx.x;
  const int r = blockIdx.x * 8 + (tid >> 5);
  const int lane = tid & 31;
  int token = x[r];
  float4 v = *(const float4*)&emb[(size_t)token * 128 + lane * 4];
  uint2 p; p.x = pk2(v.x, v.y); p.y = pk2(v.z, v.w);
  *(uint2*)&xe[(size_t)r * 128 + lane * 4] = p;
}

// ---------------------------------------------------------------------------
// K2: gates GEMM via bf16 MFMA 16x16x32.  G[m][n] = sum_k xe[m][k]*Wb[n][k]+bias[n]
// Block 256 thr = 4 waves (2x2 of 64x64). Tile 128x128, K=128 in 4 steps.
// ---------------------------------------------------------------------------
__global__ __launch_bounds__(256, 2) void gates_mfma_k(
    const u16* __restrict__ xe, const u16* __restrict__ Wb,
    const float* __restrict__ bias, u16* __restrict__ Gout)
{
  const int tid = threadIdx.x;
  const int wid = tid >> 6, l = tid & 63;
  const int wm = wid >> 1, wn = wid & 1;
  const int M0 = blockIdx.y * 128, N0 = blockIdx.x * 128;
  const int lr = l & 15, lk = l >> 4;

  f32x4 acc[4][4];
#pragma unroll
  for (int i = 0; i < 4; ++i)
#pragma unroll
    for (int j = 0; j < 4; ++j) acc[i][j] = (f32x4){0.f, 0.f, 0.f, 0.f};

#pragma unroll
  for (int ks = 0; ks < 4; ++ks) {
    bf16x8 a[4], b[4];
#pragma unroll
    for (int mi = 0; mi < 4; ++mi)
      a[mi] = *(const bf16x8*)&xe[(size_t)(M0 + wm * 64 + mi * 16 + lr) * 128 + ks * 32 + lk * 8];
#pragma unroll
    for (int ni = 0; ni < 4; ++ni)
      b[ni] = *(const bf16x8*)&Wb[(size_t)(N0 + wn * 64 + ni * 16 + lr) * 128 + ks * 32 + lk * 8];
#pragma unroll
    for (int mi = 0; mi < 4; ++mi)
#pragma unroll
      for (int ni = 0; ni < 4; ++ni)
        acc[mi][ni] = __builtin_amdgcn_mfma_f32_16x16x32_bf16(a[mi], b[ni], acc[mi][ni], 0, 0, 0);
  }

  // bias per output column (4 per lane)
  float bcol[4];
#pragma unroll
  for (int ni = 0; ni < 4; ++ni) bcol[ni] = bias[N0 + wn * 64 + ni * 16 + lr];

  // stage to LDS (padded), then coalesced store
  __shared__ u16 cs[128][136];
#pragma unroll
  for (int mi = 0; mi < 4; ++mi)
#pragma unroll
    for (int ni = 0; ni < 4; ++ni) {
      int col = wn * 64 + ni * 16 + lr;
#pragma unroll
      for (int r = 0; r < 4; ++r) {
        int row = wm * 64 + mi * 16 + lk * 4 + r;
        cs[row][col] = f2bf(acc[mi][ni][r] + bcol[ni]);
      }
    }
  __syncthreads();
  {
    int row = tid >> 1, c0 = (tid & 1) * 64;
    u16* dst = &Gout[(size_t)(M0 + row) * 1024 + N0 + c0];
#pragma unroll
    for (int q = 0; q < 8; ++q)
      *(uint4*)&dst[q * 8] = *(const uint4*)&cs[row][c0 + q * 8];
  }
}

// ---------------------------------------------------------------------------
// K3: LSTM recurrence. 256 blocks (dir,sample) x 512 threads. Thread j owns
// gate row j; Whh row held as 64 f16x2 in VGPRs (asm-pinned); h as f16 in LDS;
// dot via v_dot2_f32_f16.
// ---------------------------------------------------------------------------
__global__ __launch_bounds__(512, 2) void lstm_k(
    const u16* __restrict__ G, const u32* __restrict__ Whh16,
    u16* __restrict__ Hout)
{
  const int bid = blockIdx.x;
  const int dir = bid >> 7;
  const int b   = bid & 127;
  const int j   = threadIdx.x;

  u32 w2[64];
  const u32* wrow = Whh16 + ((size_t)dir << 15) + (size_t)j * 64;
#pragma unroll
  for (int q = 0; q < 16; ++q) {
    uint4 v = *(const uint4*)&wrow[q * 4];
    w2[4*q+0] = v.x; w2[4*q+1] = v.y; w2[4*q+2] = v.z; w2[4*q+3] = v.w;
  }
#pragma unroll
  for (int i = 0; i < 64; ++i) asm volatile("" : "+v"(w2[i]));

  __shared__ __align__(16) u32 hs2[64];   // h as 128 f16
  __shared__ float gact[512];
  if (j < 64) hs2[j] = 0u;
  float c = 0.0f;
  __syncthreads();

  const size_t gbase = (size_t)b * TT * 1024 + (size_t)dir * 512 + j;
  int t = dir ? (TT - 1) : 0;
  const int tstep = dir ? -1 : 1;
  u16 gb = G[gbase + (size_t)t * 1024];

  for (int step = 0; step < TT; ++step) {
    float gpre = bf2f(gb);
    if (step < TT - 1) gb = G[gbase + (size_t)(t + tstep) * 1024];

    float acc = 0.f;
    const uint4* h4 = (const uint4*)hs2;
#pragma unroll
    for (int q = 0; q < 16; ++q) {
      uint4 hv = h4[q];
      acc = __builtin_amdgcn_fdot2(u2h2(hv.x), u2h2(w2[4*q+0]), acc, false);
      acc = __builtin_amdgcn_fdot2(u2h2(hv.y), u2h2(w2[4*q+1]), acc, false);
      acc = __builtin_amdgcn_fdot2(u2h2(hv.z), u2h2(w2[4*q+2]), acc, false);
      acc = __builtin_amdgcn_fdot2(u2h2(hv.w), u2h2(w2[4*q+3]), acc, false);
    }
    float g = gpre + acc;
    int gate = j >> 7;
    float a = (gate == 2) ? tanhf_(g) : sigf(g);
    gact[j] = a;
    __syncthreads();
    if (j < 128) {
      float iv = gact[j], fv = gact[128 + j], gv = gact[256 + j], ov = gact[384 + j];
      c = fv * c + iv * gv;
      float hv = ov * tanhf_(c);
      ((u16*)hs2)[j] = f2h(hv);
      Hout[((size_t)(b * TT + t)) * 256 + dir * 128 + j] = f2bf(hv);
    }
    __syncthreads();
    t += tstep;
  }
}

// ---------------------------------------------------------------------------
// K4: emissions = h @ W_out^T + b_out.
// ---------------------------------------------------------------------------
__global__ __launch_bounds__(256) void emis_k(
    const u16* __restrict__ Hb, const float* __restrict__ W_out,
    const float* __restrict__ b_out, float* __restrict__ em)
{
  __shared__ __align__(16) float wl[24 * 256];
  __shared__ float bo[24];
  const int tid = threadIdx.x;
#pragma unroll
  for (int i = 0; i < 6; ++i) {
    int f4 = tid + i * 256;
    *(float4*)&wl[f4 * 4] = *(const float4*)&W_out[f4 * 4];
  }
  if (tid < 24) bo[tid] = b_out[tid];
  __syncthreads();

  const int m = blockIdx.x * 256 + tid;
  float acc[24];
#pragma unroll
  for (int tg = 0; tg < 24; ++tg) acc[tg] = bo[tg];

  const u16* hrow = Hb + (size_t)m * 256;
  for (int k8 = 0; k8 < 32; ++k8) {
    uint4 hv = *(const uint4*)(hrow + k8 * 8);
    float h0 = bf2f((u16)(hv.x & 0xffff)), h1 = bf2f((u16)(hv.x >> 16));
    float h2 = bf2f((u16)(hv.y & 0xffff)), h3 = bf2f((u16)(hv.y >> 16));
    float h4 = bf2f((u16)(hv.z & 0xffff)), h5 = bf2f((u16)(hv.z >> 16));
    float h6 = bf2f((u16)(hv.w & 0xffff)), h7 = bf2f((u16)(hv.w >> 16));
#pragma unroll
    for (int tg = 0; tg < 24; ++tg) {
      const float* wr = &wl[tg * 256 + k8 * 8];
      float4 w0 = *(const float4*)wr;
      float4 w1 = *(const float4*)(wr + 4);
      acc[tg] += h0*w0.x + h1*w0.y + h2*w0.z + h3*w0.w
               + h4*w1.x + h5*w1.y + h6*w1.z + h7*w1.w;
    }
  }
#pragma unroll
  for (int t6 = 0; t6 < 6; ++t6) {
    float4 o;
    o.x = acc[t6*4+0]; o.y = acc[t6*4+1]; o.z = acc[t6*4+2]; o.w = acc[t6*4+3];
    *(float4*)&em[(size_t)m * 24 + t6 * 4] = o;
  }
}

// ---------------------------------------------------------------------------
// K5: CRF forward scan + gold score + mean reduction. One block per sample.
// ---------------------------------------------------------------------------
__device__ __forceinline__ int get_mask(const void* mp, int idx, bool byte_mode) {
  return byte_mode ? (int)((const unsigned char*)mp)[idx] : ((const int*)mp)[idx];
}

__global__ __launch_bounds__(64) void crf_k(
    const float* __restrict__ em, const int* __restrict__ tags,
    const void* __restrict__ maskp, const float* __restrict__ trans,
    const float* __restrict__ start_tr, const float* __restrict__ end_tr,
    float* __restrict__ out)
{
  const int b = blockIdx.x;
  const int tid = threadIdx.x;
  __shared__ float tr[24 * 24];
  __shared__ float sc[24];
  __shared__ float lz;
  for (int i = tid; i < 24 * 24; i += 64) tr[i] = trans[i];
  const bool byte_mode = (*(const u32*)maskp != 1u);

  if (tid < 24) sc[tid] = start_tr[tid] + em[(size_t)(b * TT) * 24 + tid];
  __syncthreads();

  for (int t = 1; t < TT; ++t) {
    if (!get_mask(maskp, b * TT + t, byte_mode)) break;
    float ns = 0.f;
    if (tid < 24) {
      float v[24];
      float mx = -1e30f;
#pragma unroll
      for (int i = 0; i < 24; ++i) { v[i] = sc[i] + tr[i * 24 + tid]; mx = fmaxf(mx, v[i]); }
      float s = 0.f;
#pragma unroll
      for (int i = 0; i < 24; ++i) s += __expf(v[i] - mx);
      ns = em[((size_t)(b * TT + t)) * 24 + tid] + mx + __logf(s);
    }
    __syncthreads();
    if (tid < 24) sc[tid] = ns;
    __syncthreads();
  }

  if (tid == 0) {
    float mx = -1e30f;
    for (int i = 0; i < 24; ++i) mx = fmaxf(mx, sc[i] + end_tr[i]);
    float s = 0.f;
    for (int i = 0; i < 24; ++i) s += __expf(sc[i] + end_tr[i] - mx);
    lz = mx + __logf(s);
  }

  float part = 0.f;
  int cnt = 0;
  for (int t = tid; t < TT; t += 64) {
    int mt = get_mask(maskp, b * TT + t, byte_mode);
    cnt += mt;
    if (t >= 1 && mt) {
      int tp = tags[b * TT + t - 1], tc = tags[b * TT + t];
      part += tr[tp * 24 + tc] + em[((size_t)(b * TT + t)) * 24 + tc];
    }
  }
#pragma unroll
  for (int off = 32; off > 0; off >>= 1) {
    part += __shfl_down(part, off);
    cnt  += __shfl_down(cnt, off);
  }
  __syncthreads();
  if (tid == 0) {
    int t0g = tags[b * TT];
    float gold = start_tr[t0g] + em[(size_t)(b * TT) * 24 + t0g] + part;
    gold += end_tr[tags[b * TT + cnt - 1]];
    atomicAdd(out, (lz - gold) * (1.0f / 128.0f));
  }
}

// ---------------------------------------------------------------------------
extern "C" void kernel_launch(void* const* d_in, const int* in_sizes, int n_in,
                              void* d_out, int out_size, void* d_ws, size_t ws_size,
                              hipStream_t stream) {
  const int*   x     = (const int*)d_in[0];
  const int*   tags  = (const int*)d_in[1];
  const void*  mask  = d_in[2];
  const float* emb   = (const float*)d_in[3];
  const float* Wih_f = (const float*)d_in[4];
  const float* Whh_f = (const float*)d_in[5];
  const float* bih_f = (const float*)d_in[6];
  const float* bhh_f = (const float*)d_in[7];
  const float* Wih_b = (const float*)d_in[8];
  const float* Whh_b = (const float*)d_in[9];
  const float* bih_b = (const float*)d_in[10];
  const float* bhh_b = (const float*)d_in[11];
  const float* W_out = (const float*)d_in[12];
  const float* b_out = (const float*)d_in[13];
  const float* trans = (const float*)d_in[14];
  const float* st_tr = (const float*)d_in[15];
  const float* en_tr = (const float*)d_in[16];

  // Workspace: G bf16 | H bf16 | em f32 | bias f32 | Wb bf16 | Whh16 u32
  u16*   Gb    = (u16*)d_ws;                              // [65536][1024]
  u16*   Hb    = Gb + (size_t)65536 * 1024;               // [65536][256]
  float* em    = (float*)(Hb + (size_t)65536 * 256);      // [65536][24]
  float* bias  = em + (size_t)65536 * 24;                 // [1024]
  u16*   Wb    = (u16*)(bias + 1024);                     // [1024][128]
  u32*   Whh16 = (u32*)(Wb + 131072);                     // [2][512][64]
  u16*   xe    = Hb;  // alias: xe dead before lstm_k writes Hb

  prep_k<<<512, 256, 0, stream>>>(Wih_f, Wih_b, Whh_f, Whh_b,
                                  bih_f, bhh_f, bih_b, bhh_b, Wb, Whh16, bias);
  embed_k<<<8192, 256, 0, stream>>>(x, emb, xe);
  gates_mfma_k<<<dim3(8, 512), 256, 0, stream>>>(xe, Wb, bias, Gb);
  lstm_k<<<256, 512, 0, stream>>>(Gb, Whh16, Hb);
  emis_k<<<256, 256, 0, stream>>>(Hb, W_out, b_out, em);
  hipMemsetAsync(d_out, 0, sizeof(float), stream);
  crf_k<<<128, 64, 0, stream>>>(em, tags, mask, trans, st_tr, en_tr, (float*)d_out);
}

// Round 3
// 704.924 us; speedup vs baseline: 1.5082x; 1.1751x over previous
//
#include <hip/hip_runtime.h>
#include <hip/hip_bf16.h>

typedef unsigned short u16;
typedef unsigned int   u32;
typedef _Float16 half2_t __attribute__((ext_vector_type(2)));
typedef short    bf16x8 __attribute__((ext_vector_type(8)));
typedef float    f32x4  __attribute__((ext_vector_type(4)));
typedef u32      u32x4v __attribute__((ext_vector_type(4)));

// Problem dims: B=128, T=512, V=50000, NT=24, E=128, H=256, Hd=128
#define TT   512

__device__ __forceinline__ float sigf(float x)  { return 1.0f / (1.0f + __expf(-x)); }
__device__ __forceinline__ float tanhf_(float x){ return 1.0f - 2.0f / (__expf(2.0f * x) + 1.0f); }

__device__ __forceinline__ u16 f2bf(float x) {
  __hip_bfloat16 h = __float2bfloat16(x);
  return *reinterpret_cast<u16*>(&h);
}
__device__ __forceinline__ float bf2f(u16 u) { return __uint_as_float(((u32)u) << 16); }
__device__ __forceinline__ u32 pk2(float a, float b) {
  return (u32)f2bf(a) | ((u32)f2bf(b) << 16);
}
__device__ __forceinline__ u16 f2h(float x) {
  _Float16 h = (_Float16)x;
  union { _Float16 f; u16 u; } c; c.f = h; return c.u;
}
__device__ __forceinline__ half2_t u2h2(u32 v) {
  union { u32 u; half2_t h; } c; c.u = v; return c.h;
}

// ---------------------------------------------------------------------------
// K0: weight prep. Wb bf16 [1024][128]; Whh16 f16x2 [2][512][64];
// bias f32 [1024]; Wout16 f16x2 [24][128].
// ---------------------------------------------------------------------------
__global__ __launch_bounds__(256) void prep_k(
    const float* __restrict__ Wih_f, const float* __restrict__ Wih_b,
    const float* __restrict__ Whh_f, const float* __restrict__ Whh_b,
    const float* __restrict__ bih_f, const float* __restrict__ bhh_f,
    const float* __restrict__ bih_b, const float* __restrict__ bhh_b,
    const float* __restrict__ W_out,
    u16* __restrict__ Wb, u32* __restrict__ Whh16, float* __restrict__ bias,
    u32* __restrict__ Wout16)
{
  int i = blockIdx.x * 256 + threadIdx.x;   // 131072 threads
  {
    int n = i >> 7, k = i & 127;
    float v = (n < 512) ? Wih_f[n * 128 + k] : Wih_b[(n - 512) * 128 + k];
    Wb[i] = f2bf(v);
  }
  if (i < 65536) {
    int d = i >> 15, rem = i & 32767, r = rem >> 6, kp = rem & 63;
    const float* W = d ? Whh_b : Whh_f;
    float f0 = W[r * 128 + 2 * kp], f1 = W[r * 128 + 2 * kp + 1];
    Whh16[i] = (u32)f2h(f0) | ((u32)f2h(f1) << 16);
  }
  if (i < 1024) {
    int d = i >> 9, jj = i & 511;
    bias[i] = d ? (bih_b[jj] + bhh_b[jj]) : (bih_f[jj] + bhh_f[jj]);
  }
  if (i < 3072) {
    Wout16[i] = (u32)f2h(W_out[2 * i]) | ((u32)f2h(W_out[2 * i + 1]) << 16);
  }
}

// ---------------------------------------------------------------------------
// K1: embedding gather -> bf16 xe [65536][128]
// ---------------------------------------------------------------------------
__global__ __launch_bounds__(256) void embed_k(
    const int* __restrict__ x, const float* __restrict__ emb, u16* __restrict__ xe)
{
  const int tid = threadIdx.x;
  const int r = blockIdx.x * 8 + (tid >> 5);
  const int lane = tid & 31;
  int token = x[r];
  float4 v = *(const float4*)&emb[(size_t)token * 128 + lane * 4];
  uint2 p; p.x = pk2(v.x, v.y); p.y = pk2(v.z, v.w);
  *(uint2*)&xe[(size_t)r * 128 + lane * 4] = p;
}

// ---------------------------------------------------------------------------
// K2: gates GEMM via bf16 MFMA 16x16x32.  G[m][n] = sum_k xe[m][k]*Wb[n][k]+bias[n]
// ---------------------------------------------------------------------------
__global__ __launch_bounds__(256, 2) void gates_mfma_k(
    const u16* __restrict__ xe, const u16* __restrict__ Wb,
    const float* __restrict__ bias, u16* __restrict__ Gout)
{
  const int tid = threadIdx.x;
  const int wid = tid >> 6, l = tid & 63;
  const int wm = wid >> 1, wn = wid & 1;
  const int M0 = blockIdx.y * 128, N0 = blockIdx.x * 128;
  const int lr = l & 15, lk = l >> 4;

  f32x4 acc[4][4];
#pragma unroll
  for (int i = 0; i < 4; ++i)
#pragma unroll
    for (int j = 0; j < 4; ++j) acc[i][j] = (f32x4){0.f, 0.f, 0.f, 0.f};

#pragma unroll
  for (int ks = 0; ks < 4; ++ks) {
    bf16x8 a[4], b[4];
#pragma unroll
    for (int mi = 0; mi < 4; ++mi)
      a[mi] = *(const bf16x8*)&xe[(size_t)(M0 + wm * 64 + mi * 16 + lr) * 128 + ks * 32 + lk * 8];
#pragma unroll
    for (int ni = 0; ni < 4; ++ni)
      b[ni] = *(const bf16x8*)&Wb[(size_t)(N0 + wn * 64 + ni * 16 + lr) * 128 + ks * 32 + lk * 8];
#pragma unroll
    for (int mi = 0; mi < 4; ++mi)
#pragma unroll
      for (int ni = 0; ni < 4; ++ni)
        acc[mi][ni] = __builtin_amdgcn_mfma_f32_16x16x32_bf16(a[mi], b[ni], acc[mi][ni], 0, 0, 0);
  }

  float bcol[4];
#pragma unroll
  for (int ni = 0; ni < 4; ++ni) bcol[ni] = bias[N0 + wn * 64 + ni * 16 + lr];

  __shared__ u16 cs[128][136];
#pragma unroll
  for (int mi = 0; mi < 4; ++mi)
#pragma unroll
    for (int ni = 0; ni < 4; ++ni) {
      int col = wn * 64 + ni * 16 + lr;
#pragma unroll
      for (int r = 0; r < 4; ++r) {
        int row = wm * 64 + mi * 16 + lk * 4 + r;
        cs[row][col] = f2bf(acc[mi][ni][r] + bcol[ni]);
      }
    }
  __syncthreads();
  {
    int row = tid >> 1, c0 = (tid & 1) * 64;
    u16* dst = &Gout[(size_t)(M0 + row) * 1024 + N0 + c0];
#pragma unroll
    for (int q = 0; q < 8; ++q)
      *(uint4*)&dst[q * 8] = *(const uint4*)&cs[row][c0 + q * 8];
  }
}

// ---------------------------------------------------------------------------
// K3: LSTM recurrence. 256 blocks (dir,sample) x 256 threads.
// Thread (r,hi) owns gate rows: hi=0 -> (i_r, f_r), hi=1 -> (g_r, o_r).
// 2x64 u32 f16-pair weights in NAMED registers (asm-pinned). h f16 in LDS.
// ---------------------------------------------------------------------------
__global__ __launch_bounds__(256, 1) void lstm_k(
    const u16* __restrict__ G, const u32* __restrict__ Whh16,
    u16* __restrict__ Hout)
{
  const int bid = blockIdx.x;
  const int dir = bid >> 7, b = bid & 127;
  const int tid = threadIdx.x;
  const int r   = tid & 127;
  const int hi  = tid >> 7;          // wave-uniform (waves 0,1 vs 2,3)
  const int g0  = r + hi * 256;      // i_r or g_r
  const int g1  = g0 + 128;          // f_r or o_r

  const u32* w0p = Whh16 + ((size_t)dir << 15) + (size_t)g0 * 64;
  const u32* w1p = Whh16 + ((size_t)dir << 15) + (size_t)g1 * 64;

#define LDQ(n) u32x4v q##n = *(const u32x4v*)(w0p + 4*(n)); \
               u32x4v p##n = *(const u32x4v*)(w1p + 4*(n));
  LDQ(0)  LDQ(1)  LDQ(2)  LDQ(3)  LDQ(4)  LDQ(5)  LDQ(6)  LDQ(7)
  LDQ(8)  LDQ(9)  LDQ(10) LDQ(11) LDQ(12) LDQ(13) LDQ(14) LDQ(15)
#undef LDQ
#define PIN(a,b,c,d) asm volatile("" : "+v"(a), "+v"(b), "+v"(c), "+v"(d));
  PIN(q0,q1,q2,q3)   PIN(q4,q5,q6,q7)   PIN(q8,q9,q10,q11)   PIN(q12,q13,q14,q15)
  PIN(p0,p1,p2,p3)   PIN(p4,p5,p6,p7)   PIN(p8,p9,p10,p11)   PIN(p12,p13,p14,p15)
#undef PIN

  __shared__ __align__(16) u32 hs2[64];   // h as 128 f16
  __shared__ float gact[512];
  if (tid < 64) hs2[tid] = 0u;
  float c = 0.0f;
  __syncthreads();

  const u16* gp = G + (size_t)b * TT * 1024 + (size_t)dir * 512;
  int t = dir ? (TT - 1) : 0;
  const int ts = dir ? -1 : 1;
  u16 gb0 = gp[(size_t)t * 1024 + g0];
  u16 gb1 = gp[(size_t)t * 1024 + g1];

  for (int step = 0; step < TT; ++step) {
    float gpre0 = bf2f(gb0), gpre1 = bf2f(gb1);
    if (step < TT - 1) {
      gb0 = gp[(size_t)(t + ts) * 1024 + g0];
      gb1 = gp[(size_t)(t + ts) * 1024 + g1];
    }

    float a00 = 0.f, a01 = 0.f, a10 = 0.f, a11 = 0.f;
    const u32x4v* h4 = (const u32x4v*)hs2;
#define DOT(n) { u32x4v hv = h4[n]; \
    a00 = __builtin_amdgcn_fdot2(u2h2(hv.x), u2h2(q##n.x), a00, false); \
    a00 = __builtin_amdgcn_fdot2(u2h2(hv.y), u2h2(q##n.y), a00, false); \
    a01 = __builtin_amdgcn_fdot2(u2h2(hv.z), u2h2(q##n.z), a01, false); \
    a01 = __builtin_amdgcn_fdot2(u2h2(hv.w), u2h2(q##n.w), a01, false); \
    a10 = __builtin_amdgcn_fdot2(u2h2(hv.x), u2h2(p##n.x), a10, false); \
    a10 = __builtin_amdgcn_fdot2(u2h2(hv.y), u2h2(p##n.y), a10, false); \
    a11 = __builtin_amdgcn_fdot2(u2h2(hv.z), u2h2(p##n.z), a11, false); \
    a11 = __builtin_amdgcn_fdot2(u2h2(hv.w), u2h2(p##n.w), a11, false); }
    DOT(0)  DOT(1)  DOT(2)  DOT(3)  DOT(4)  DOT(5)  DOT(6)  DOT(7)
    DOT(8)  DOT(9)  DOT(10) DOT(11) DOT(12) DOT(13) DOT(14) DOT(15)
#undef DOT
    float v0 = gpre0 + a00 + a01;
    float v1 = gpre1 + a10 + a11;

    float act0, act1;
    if (hi == 0) { act0 = sigf(v0);   act1 = sigf(v1); }   // i, f
    else         { act0 = tanhf_(v0); act1 = sigf(v1); }   // g, o
    gact[g0] = act0; gact[g1] = act1;
    __syncthreads();
    if (hi == 0) {
      float iv = gact[r], fv = gact[128 + r], gv = gact[256 + r], ov = gact[384 + r];
      c = fv * c + iv * gv;
      float hvv = ov * tanhf_(c);
      ((u16*)hs2)[r] = f2h(hvv);
      Hout[((size_t)(b * TT + t)) * 256 + dir * 128 + r] = f2h(hvv);
    }
    __syncthreads();
    t += ts;
  }
}

// ---------------------------------------------------------------------------
// K4: emissions = h @ W_out^T + b_out.  H is f16, W_out f16-packed in LDS,
// fdot2 inner product. em f32.
// ---------------------------------------------------------------------------
__global__ __launch_bounds__(256) void emis_k(
    const u16* __restrict__ Hb, const u32* __restrict__ Wout16,
    const float* __restrict__ b_out, float* __restrict__ em)
{
  __shared__ __align__(16) u32 wl2[24 * 128];   // 12 KB
  __shared__ float bo[24];
  const int tid = threadIdx.x;
  for (int i = tid; i < 3072; i += 256) wl2[i] = Wout16[i];
  if (tid < 24) bo[tid] = b_out[tid];
  __syncthreads();

  const int m = blockIdx.x * 256 + tid;
  float acc[24];
#pragma unroll
  for (int tg = 0; tg < 24; ++tg) acc[tg] = bo[tg];

  const u32* h2 = (const u32*)(Hb + (size_t)m * 256);
  for (int ck = 0; ck < 16; ++ck) {          // 8 f16 per chunk
    uint4 hv = *(const uint4*)(h2 + ck * 4);
#pragma unroll
    for (int tg = 0; tg < 24; ++tg) {
      u32x4v wv = *(const u32x4v*)&wl2[tg * 128 + ck * 4];
      float a = acc[tg];
      a = __builtin_amdgcn_fdot2(u2h2(hv.x), u2h2(wv.x), a, false);
      a = __builtin_amdgcn_fdot2(u2h2(hv.y), u2h2(wv.y), a, false);
      a = __builtin_amdgcn_fdot2(u2h2(hv.z), u2h2(wv.z), a, false);
      a = __builtin_amdgcn_fdot2(u2h2(hv.w), u2h2(wv.w), a, false);
      acc[tg] = a;
    }
  }
#pragma unroll
  for (int t6 = 0; t6 < 6; ++t6) {
    float4 o;
    o.x = acc[t6*4+0]; o.y = acc[t6*4+1]; o.z = acc[t6*4+2]; o.w = acc[t6*4+3];
    *(float4*)&em[(size_t)m * 24 + t6 * 4] = o;
  }
}

// ---------------------------------------------------------------------------
// K5: CRF forward scan + gold score + mean reduction. One block (1 wave) per
// sample. Mask folded into a single length (monotone prefix) computed once.
// em rows prefetched one step ahead. logsumexp split across lane pairs.
// ---------------------------------------------------------------------------
__device__ __forceinline__ int get_mask(const void* mp, int idx, bool byte_mode) {
  return byte_mode ? (int)((const unsigned char*)mp)[idx] : ((const int*)mp)[idx];
}

__global__ __launch_bounds__(64) void crf_k(
    const float* __restrict__ em, const int* __restrict__ tags,
    const void* __restrict__ maskp, const float* __restrict__ trans,
    const float* __restrict__ start_tr, const float* __restrict__ end_tr,
    float* __restrict__ out)
{
  const int b = blockIdx.x;
  const int tid = threadIdx.x;
  __shared__ float tr[24 * 24];
  __shared__ float scs[24];
  for (int i = tid; i < 24 * 24; i += 64) tr[i] = trans[i];
  const bool byte_mode = (*(const u32*)maskp != 1u);

  // sequence length (mask is a monotone prefix)
  int cnt = 0;
  for (int t = tid; t < TT; t += 64) cnt += get_mask(maskp, b * TT + t, byte_mode);
#pragma unroll
  for (int off = 32; off > 0; off >>= 1) cnt += __shfl_down(cnt, off);
  cnt = __shfl(cnt, 0);

  if (tid < 24) scs[tid] = start_tr[tid] + em[(size_t)(b * TT) * 24 + tid];
  __syncthreads();

  const int j = tid >> 1, h = tid & 1;       // lanes 0..47 active in scan
  const bool act = (tid < 48);
  float em_next = 0.f;
  if (act && h == 0 && cnt > 1) em_next = em[(size_t)(b * TT + 1) * 24 + j];

  for (int t = 1; t < cnt; ++t) {
    float em_cur = em_next;
    if (act && h == 0 && t + 1 < cnt) em_next = em[(size_t)(b * TT + t + 1) * 24 + j];
    float ns = 0.f;
    if (act) {
      const int base = h * 12;
      float vv[12];
      float mx = -1e30f;
#pragma unroll
      for (int i = 0; i < 12; ++i) {
        vv[i] = scs[base + i] + tr[(base + i) * 24 + j];
        mx = fmaxf(mx, vv[i]);
      }
      float s = 0.f;
#pragma unroll
      for (int i = 0; i < 12; ++i) s += __expf(vv[i] - mx);
      float mo = __shfl_xor(mx, 1), so = __shfl_xor(s, 1);
      float M = fmaxf(mx, mo);
      s = s * __expf(mx - M) + so * __expf(mo - M);
      ns = em_cur + M + __logf(s);
    }
    __syncthreads();
    if (act && h == 0) scs[j] = ns;
    __syncthreads();
  }

  float lzv = 0.f;
  if (tid == 0) {
    float mx = -1e30f;
    for (int i = 0; i < 24; ++i) mx = fmaxf(mx, scs[i] + end_tr[i]);
    float s = 0.f;
    for (int i = 0; i < 24; ++i) s += __expf(scs[i] + end_tr[i] - mx);
    lzv = mx + __logf(s);
  }

  // gold score (uses cnt as the prefix length)
  float part = 0.f;
  for (int t = tid; t < TT; t += 64) {
    if (t >= 1 && t < cnt) {
      int tp = tags[b * TT + t - 1], tc = tags[b * TT + t];
      part += tr[tp * 24 + tc] + em[((size_t)(b * TT + t)) * 24 + tc];
    }
  }
#pragma unroll
  for (int off = 32; off > 0; off >>= 1) part += __shfl_down(part, off);
  if (tid == 0) {
    int t0g = tags[b * TT];
    float gold = start_tr[t0g] + em[(size_t)(b * TT) * 24 + t0g] + part;
    gold += end_tr[tags[b * TT + cnt - 1]];
    atomicAdd(out, (lzv - gold) * (1.0f / 128.0f));
  }
}

// ---------------------------------------------------------------------------
extern "C" void kernel_launch(void* const* d_in, const int* in_sizes, int n_in,
                              void* d_out, int out_size, void* d_ws, size_t ws_size,
                              hipStream_t stream) {
  const int*   x     = (const int*)d_in[0];
  const int*   tags  = (const int*)d_in[1];
  const void*  mask  = d_in[2];
  const float* emb   = (const float*)d_in[3];
  const float* Wih_f = (const float*)d_in[4];
  const float* Whh_f = (const float*)d_in[5];
  const float* bih_f = (const float*)d_in[6];
  const float* bhh_f = (const float*)d_in[7];
  const float* Wih_b = (const float*)d_in[8];
  const float* Whh_b = (const float*)d_in[9];
  const float* bih_b = (const float*)d_in[10];
  const float* bhh_b = (const float*)d_in[11];
  const float* W_out = (const float*)d_in[12];
  const float* b_out = (const float*)d_in[13];
  const float* trans = (const float*)d_in[14];
  const float* st_tr = (const float*)d_in[15];
  const float* en_tr = (const float*)d_in[16];

  u16*   Gb     = (u16*)d_ws;                              // [65536][1024] bf16
  u16*   Hb     = Gb + (size_t)65536 * 1024;               // [65536][256]  f16
  float* em     = (float*)(Hb + (size_t)65536 * 256);      // [65536][24]   f32
  float* bias   = em + (size_t)65536 * 24;                 // [1024]
  u16*   Wb     = (u16*)(bias + 1024);                     // [1024][128]   bf16
  u32*   Whh16  = (u32*)(Wb + 131072);                     // [2][512][64]  f16x2
  u32*   Wout16 = Whh16 + 65536;                           // [24][128]     f16x2
  u16*   xe     = Hb;  // alias: xe dead before lstm_k writes Hb

  prep_k<<<512, 256, 0, stream>>>(Wih_f, Wih_b, Whh_f, Whh_b,
                                  bih_f, bhh_f, bih_b, bhh_b, W_out,
                                  Wb, Whh16, bias, Wout16);
  embed_k<<<8192, 256, 0, stream>>>(x, emb, xe);
  gates_mfma_k<<<dim3(8, 512), 256, 0, stream>>>(xe, Wb, bias, Gb);
  lstm_k<<<256, 256, 0, stream>>>(Gb, Whh16, Hb);
  emis_k<<<256, 256, 0, stream>>>(Hb, Wout16, b_out, em);
  hipMemsetAsync(d_out, 0, sizeof(float), stream);
  crf_k<<<128, 64, 0, stream>>>(em, tags, mask, trans, st_tr, en_tr, (float*)d_out);
}